// Round 8
// baseline (186.650 us; speedup 1.0000x reference)
//
#include <hip/hip_runtime.h>
#include <hip/hip_bf16.h>
#include <cstdint>

// LocalRNN: B=16 L=1024 D=256 H=256 K=16 (GRU over K-window per position).
// FP32 in/out. Round-18 = r17 (16 waves x 16 cols, imm-offset GRU loop,
// 132.4us PROVEN no-spill) + grz/gn MERGED into one uint2 array gq
// (stride 261 u64): per cell ONE ds_read_b64 replaces b32+u16 (-8 LDS
// instrs/step/wave, -25% scalar ops), removes gn's structural 4-way
// conflict, drops one base pointer. LDS 157.3KB <= 160 (1 block/CU as
// before -- occupancy is hard-capped at 16 waves/CU; 2 blocks would need
// <=64 regs/wave, impossible with wf=96).
// Ledger:
//  r10: +12 regs at (512,2) => wf spills, FETCH 15MB->1.7GB.
//  r12: xs/hl XOR-swizzle => conflicts UNCHANGED => conflicts are from the
//       SCALAR epilogue ops, not b128 af reads. addr temps spilled. REVERT.
//  r13: af-hoist 6 accs => spill (WRITE 233MB). REVERT.
//  r14: MT=16 LDS diet => occupancy cap is REGISTERS not LDS. REVERT.
//  r15: 16w x 16c => occ 44% PROVEN, spill (309MB). r16 diet: still ~6 over.
//  r17: imm-offset addressing => FIT. 132.4us, WRITE 18.4MB, occ 42%. BASE.
//  Spill signature = WRITE_SIZE >> 18.4MB. Watch it every round.

#define B_  16
#define L_  1024
#define D_  256
#define H_  256
#define K_  16
#define MT  32             // positions per block
#define NROW 47            // gi rows per block = MT + K - 1
#define HS  264            // h/xs LDS row stride (u16)
#define GQS 261            // gq LDS row stride (uint2) -> quad rows at +8 banks
#define HB  (MT * HS)      // h buffer stride (u16) = 8448
#define L2E 1.44269504f

typedef __attribute__((ext_vector_type(8))) short  bf16x8;
typedef __attribute__((ext_vector_type(4))) float  floatx4;
typedef unsigned short ush;

#if __has_builtin(__builtin_amdgcn_exp2f)
#define fexp2(x) __builtin_amdgcn_exp2f(x)
#else
#define fexp2(x) exp2f(x)
#endif

__device__ __forceinline__ float bf2f(ush u) {
    union { unsigned int i; float f; } v; v.i = ((unsigned int)u) << 16; return v.f;
}
__device__ __forceinline__ ush f2bf(float f) {
    union { float f; unsigned int i; } v; v.f = f;
    unsigned int x = v.i;
    return (ush)((x + 0x7FFFu + ((x >> 16) & 1u)) >> 16);  // RNE
}
__device__ __forceinline__ unsigned int pk2(float a, float b) {
    union { __hip_bfloat162 v; unsigned int u; } c;
    c.v = __float22bfloat162_rn(make_float2(a, b));  // lo=a, hi=b
    return c.u;
}
__device__ __forceinline__ float rcpf(float x) { return __builtin_amdgcn_rcpf(x); }

// ---- wprep (coalesced): thread = 8-elem chunk of one weight row ------------
// dst frag layout (per r7): e = ((w*6 + gate*2 + sloc)*8 + ks)*512 + lane*8 + j
#define NCHUNK 24576   // 768 rows * 32 chunks, per matrix
__global__ __launch_bounds__(256) void wprep(const float* __restrict__ Wih,
                                             const float* __restrict__ Whh,
                                             ush* __restrict__ Wir,
                                             ush* __restrict__ Wr) {
    int idx = blockIdx.x * 256 + threadIdx.x;      // 0 .. 2*NCHUNK-1
    const float* src = (idx < NCHUNK) ? Whh : Wih;
    ush* dst         = (idx < NCHUNK) ? Wr  : Wir;
    int c = (idx < NCHUNK) ? idx : idx - NCHUNK;
    int srow = c >> 5, ch = c & 31;
    int gate = srow >> 8, rr = srow & 255;
    int w    = rr >> 5;
    int sloc = (rr >> 4) & 1;
    int l16  = rr & 15;
    int ks   = ch >> 2;          // scol0 = ch*8 -> ks = scol0/32
    int quad = ch & 3;           // (scol0 & 31) / 8
    int lane = quad * 16 + l16;
    int e0 = (((w * 6 + gate * 2 + sloc) * 8 + ks) << 9) + lane * 8;
    float scl = (gate < 2) ? -L2E : 2.f * L2E;
    const float* s = src + srow * 256 + ch * 8;
    float4 v0 = *(const float4*)(s);
    float4 v1 = *(const float4*)(s + 4);
    *(uint4*)(dst + e0) = make_uint4(pk2(v0.x * scl, v0.y * scl),
                                     pk2(v0.z * scl, v0.w * scl),
                                     pk2(v1.x * scl, v1.y * scl),
                                     pk2(v1.z * scl, v1.w * scl));
}

// ---- fused kernel: 16 waves x 16 cols, imm-offset GRU loop, gq merged ------
__global__ __launch_bounds__(1024, 4) void rnn_fused(const float* __restrict__ x,
                                                     const ush* __restrict__ Wir,
                                                     const ush* __restrict__ Wr,
                                                     const float* __restrict__ bih,
                                                     const float* __restrict__ bhh,
                                                     float* __restrict__ out) {
    __shared__ __align__(16) ush xs[48 * HS];       // 25,344 B  staged x (bf16)
    __shared__ __align__(16) uint2 gq[NROW * GQS];  // 98,136 B  (rz pair, n)
    __shared__ __align__(16) ush hl[2][HB];         // 33,792 B  (tot 157,272)

    int tid  = threadIdx.x;
    int wave = tid >> 6, lane = tid & 63;
    int l16  = lane & 15, quad = lane >> 4, quad4 = quad * 4;
    int p0   = blockIdx.x * MT;
    int bb   = p0 >> 10, lb = p0 & 1023;
    int col  = wave * 16 + l16;               // thread's single hidden col
    // weight fragment base: frag = (wave>>1)*6 + gate*2 + (wave&1)
    int fb   = ((wave >> 1) * 6 + (wave & 1)) * 4096 + lane * 8;

    // ---- stage x rows j=0..47 (token lb-15+j, zero-padded) + zero h[0] -----
    {
        const float4* x4 = (const float4*)x;
        for (int idx = tid; idx < 48 * 64; idx += 1024) {
            int j = idx >> 6, c = idx & 63;
            int tok = lb - 15 + j;
            float4 v = make_float4(0.f, 0.f, 0.f, 0.f);
            if (tok >= 0 && tok < L_) v = x4[(size_t)((bb << 10) + tok) * 64 + c];
            *(uint2*)(xs + j * HS + c * 4) = make_uint2(pk2(v.x, v.y), pk2(v.z, v.w));
        }
        for (int idx = tid; idx < HB / 2; idx += 1024)
            ((unsigned int*)(&hl[0][0]))[idx] = 0u;
    }
    __syncthreads();

    // ---- in-block gi GEMM: 48 rows x (3 gate-frags for this wave) ----------
    {
        floatx4 gacc[3][3];  // [m-tile][gate]
        {
            float ir = -L2E * (bih[col] + bhh[col]);
            float iz = -L2E * (bih[256 + col] + bhh[256 + col]);
            float in_ = 2.f * L2E * bih[512 + col];
#pragma unroll
            for (int mt = 0; mt < 3; mt++) {
                gacc[mt][0] = (floatx4){ir, ir, ir, ir};
                gacc[mt][1] = (floatx4){iz, iz, iz, iz};
                gacc[mt][2] = (floatx4){in_, in_, in_, in_};
            }
        }
        const ush* wp = Wir + fb;
#pragma unroll
        for (int ks = 0; ks < 8; ks++) {
            bf16x8 bw[3];
#pragma unroll
            for (int g = 0; g < 3; g++)
                bw[g] = *(const bf16x8*)(wp + g * 8192 + ks * 512);
#pragma unroll
            for (int mt = 0; mt < 3; mt++) {
                bf16x8 af = *(const bf16x8*)(xs + (mt * 16 + l16) * HS + ks * 32 + quad * 8);
#pragma unroll
                for (int g = 0; g < 3; g++)
                    gacc[mt][g] = __builtin_amdgcn_mfma_f32_16x16x32_bf16(
                        af, bw[g], gacc[mt][g], 0, 0, 0);
            }
        }
        // pack into gq (C/D: col=l16 -> col, row=quad4+r -> window row)
#pragma unroll
        for (int mt = 0; mt < 3; mt++)
#pragma unroll
            for (int r = 0; r < 4; r++) {
                int j = mt * 16 + quad4 + r;
                if (j < NROW) {
                    gq[j * GQS + col] = make_uint2(
                        pk2(gacc[mt][0][r], gacc[mt][1][r]),
                        (unsigned int)f2bf(gacc[mt][2][r]));
                }
            }
    }

    // ---- W_hh fragments (scaled) -> 96 regs, held across all 16 steps ------
    bf16x8 wf[3][8];
    {
        const ush* wp = Wr + fb;
#pragma unroll
        for (int g = 0; g < 3; g++)
#pragma unroll
            for (int ks = 0; ks < 8; ks++)
                wf[g][ks] = *(const bf16x8*)(wp + g * 8192 + ks * 512);
    }
    float bn = 2.f * L2E * bhh[512 + col];
    __syncthreads();  // gi pack + h[0] zero visible

    // ---- GRU loop: 3 base pointers, ALL in-loop offsets are immediates -----
    const ush*   hab = &hl[0][0] + l16 * HS + quad * 8;   // A-frag base
    ush*         hwb = &hl[0][0] + quad4 * HS + col;      // h-row base
    const uint2* gqp = gq + quad4 * GQS + col;            // gate base

    // One GRU step. RD/WR are u16 imm offsets selecting the h double buffer.
#define GRU_STEP(RD, WR)                                                      \
    {                                                                         \
        _Pragma("unroll")                                                     \
        for (int T = 0; T < 2; T++) {                                         \
            floatx4 a0 = (floatx4){0.f, 0.f, 0.f, 0.f};                       \
            floatx4 a1 = (floatx4){0.f, 0.f, 0.f, 0.f};                       \
            floatx4 a2 = (floatx4){bn, bn, bn, bn};                           \
            _Pragma("unroll")                                                 \
            for (int ks = 0; ks < 8; ks++) {                                  \
                bf16x8 af = *(const bf16x8*)(hab + (RD) + T * (16 * HS) + ks * 32); \
                a0 = __builtin_amdgcn_mfma_f32_16x16x32_bf16(af, wf[0][ks], a0, 0, 0, 0); \
                a1 = __builtin_amdgcn_mfma_f32_16x16x32_bf16(af, wf[1][ks], a1, 0, 0, 0); \
                a2 = __builtin_amdgcn_mfma_f32_16x16x32_bf16(af, wf[2][ks], a2, 0, 0, 0); \
            }                                                                 \
            _Pragma("unroll")                                                 \
            for (int r = 0; r < 4; r++) {                                     \
                uint2 g = gqp[(T * 16 + r) * GQS];                            \
                float ar = a0[r] + __uint_as_float(g.x << 16);                \
                float az = a1[r] + __uint_as_float(g.x & 0xffff0000u);        \
                float rg = rcpf(1.f + fexp2(ar));                             \
                float zg = rcpf(1.f + fexp2(az));                            \
                float u  = bf2f((ush)g.y) + rg * a2[r];                       \
                float ng = 1.f - 2.f * rcpf(fexp2(u) + 1.f);                  \
                float hprev = bf2f(hwb[(RD) + T * (16 * HS) + r * HS]);       \
                float hv = ng + zg * (hprev - ng);                            \
                hwb[(WR) + T * (16 * HS) + r * HS] = f2bf(hv);                \
            }                                                                 \
        }                                                                     \
        __syncthreads();                                                      \
        gqp += GQS;                                                           \
    }

#pragma unroll 1
    for (int tt = 0; tt < K_ / 2; tt++) {
        GRU_STEP(0, HB);   // even t: read hl[0], write hl[1]
        GRU_STEP(HB, 0);   // odd  t: read hl[1], write hl[0]
    }
#undef GRU_STEP

    // ---- final h (in hl[0] after 16 steps) -> out (fp32), own cells --------
#pragma unroll
    for (int T = 0; T < 2; T++)
#pragma unroll
        for (int r = 0; r < 4; r++) {
            int row = T * 16 + quad4 + r;
            out[(size_t)(p0 + row) * H_ + col] = bf2f(hl[0][row * HS + col]);
        }
}

extern "C" void kernel_launch(void* const* d_in, const int* in_sizes, int n_in,
                              void* d_out, int out_size, void* d_ws, size_t ws_size,
                              hipStream_t stream) {
    const float* x    = (const float*)d_in[0];
    const float* W_ih = (const float*)d_in[1];
    const float* W_hh = (const float*)d_in[2];
    const float* b_ih = (const float*)d_in[3];
    const float* b_hh = (const float*)d_in[4];
    float* out = (float*)d_out;

    // ws layout (bytes): Wir 393,216 | Wr 393,216  (scaled, wave-blocked)
    char* ws = (char*)d_ws;
    ush* Wir = (ush*)ws;
    ush* Wr  = (ush*)(ws + 393216);

    wprep<<<2 * NCHUNK / 256, 256, 0, stream>>>(W_ih, W_hh, Wir, Wr);
    rnn_fused<<<B_ * L_ / MT, 1024, 0, stream>>>(x, Wir, Wr, b_ih, b_hh, out);
}

// Round 9
// 182.874 us; speedup vs baseline: 1.0207x; 1.0207x over previous
//
#include <hip/hip_runtime.h>
#include <hip/hip_bf16.h>
#include <cstdint>

// LocalRNN: B=16 L=1024 D=256 H=256 K=16 (GRU over K-window per position).
// FP32 in/out. Round-19 = r18 (16 waves x 16 cols, imm-offset GRU loop, gq
// merged, 132.4us) + epilogue VALU diet: cells processed as even/odd PAIRS,
// one v_cvt_pk_bf16_f32 (via pk2, already proven in this kernel) replaces
// two manual 4-op RNE f2bf sequences. ~32 fewer VALU ops/thread/step (~10%
// of VALU issue, the largest measured pipe at 50% busy).
// Ledger:
//  r11 (2 w/SIMD) 143us vs r17 (4 w/SIMD, same per-CU work) 132us: +8% only
//    => ~90% saturated per-CU resource; counters say VALU issue (50% busy).
//  r12: xs/hl swizzle => conflicts UNCHANGED (b128 af aliasing, costless).
//  r13/r15/r16: register experiments => spills. r17 imm-offset => FIT.
//  r18: gq merge (-8 scalar LDS ops/step) => NEUTRAL => scalar LDS not
//    critical. VALU is the target now.
//  Spill signature = WRITE_SIZE >> 24.5MB. Watch it every round.

#define B_  16
#define L_  1024
#define D_  256
#define H_  256
#define K_  16
#define MT  32             // positions per block
#define NROW 47            // gi rows per block = MT + K - 1
#define HS  264            // h/xs LDS row stride (u16)
#define GQS 261            // gq LDS row stride (uint2) -> quad rows at +8 banks
#define HB  (MT * HS)      // h buffer stride (u16) = 8448
#define L2E 1.44269504f

typedef __attribute__((ext_vector_type(8))) short  bf16x8;
typedef __attribute__((ext_vector_type(4))) float  floatx4;
typedef unsigned short ush;

#if __has_builtin(__builtin_amdgcn_exp2f)
#define fexp2(x) __builtin_amdgcn_exp2f(x)
#else
#define fexp2(x) exp2f(x)
#endif

__device__ __forceinline__ float bf2f(ush u) {
    union { unsigned int i; float f; } v; v.i = ((unsigned int)u) << 16; return v.f;
}
__device__ __forceinline__ ush f2bf(float f) {
    union { float f; unsigned int i; } v; v.f = f;
    unsigned int x = v.i;
    return (ush)((x + 0x7FFFu + ((x >> 16) & 1u)) >> 16);  // RNE
}
__device__ __forceinline__ unsigned int pk2(float a, float b) {
    union { __hip_bfloat162 v; unsigned int u; } c;
    c.v = __float22bfloat162_rn(make_float2(a, b));  // lo=a, hi=b (v_cvt_pk_bf16_f32)
    return c.u;
}
__device__ __forceinline__ float rcpf(float x) { return __builtin_amdgcn_rcpf(x); }

// ---- wprep (coalesced): thread = 8-elem chunk of one weight row ------------
// dst frag layout (per r7): e = ((w*6 + gate*2 + sloc)*8 + ks)*512 + lane*8 + j
#define NCHUNK 24576   // 768 rows * 32 chunks, per matrix
__global__ __launch_bounds__(256) void wprep(const float* __restrict__ Wih,
                                             const float* __restrict__ Whh,
                                             ush* __restrict__ Wir,
                                             ush* __restrict__ Wr) {
    int idx = blockIdx.x * 256 + threadIdx.x;      // 0 .. 2*NCHUNK-1
    const float* src = (idx < NCHUNK) ? Whh : Wih;
    ush* dst         = (idx < NCHUNK) ? Wr  : Wir;
    int c = (idx < NCHUNK) ? idx : idx - NCHUNK;
    int srow = c >> 5, ch = c & 31;
    int gate = srow >> 8, rr = srow & 255;
    int w    = rr >> 5;
    int sloc = (rr >> 4) & 1;
    int l16  = rr & 15;
    int ks   = ch >> 2;          // scol0 = ch*8 -> ks = scol0/32
    int quad = ch & 3;           // (scol0 & 31) / 8
    int lane = quad * 16 + l16;
    int e0 = (((w * 6 + gate * 2 + sloc) * 8 + ks) << 9) + lane * 8;
    float scl = (gate < 2) ? -L2E : 2.f * L2E;
    const float* s = src + srow * 256 + ch * 8;
    float4 v0 = *(const float4*)(s);
    float4 v1 = *(const float4*)(s + 4);
    *(uint4*)(dst + e0) = make_uint4(pk2(v0.x * scl, v0.y * scl),
                                     pk2(v0.z * scl, v0.w * scl),
                                     pk2(v1.x * scl, v1.y * scl),
                                     pk2(v1.z * scl, v1.w * scl));
}

// ---- fused kernel: 16 waves x 16 cols, imm-offset GRU loop, gq merged ------
__global__ __launch_bounds__(1024, 4) void rnn_fused(const float* __restrict__ x,
                                                     const ush* __restrict__ Wir,
                                                     const ush* __restrict__ Wr,
                                                     const float* __restrict__ bih,
                                                     const float* __restrict__ bhh,
                                                     float* __restrict__ out) {
    __shared__ __align__(16) ush xs[48 * HS];       // 25,344 B  staged x (bf16)
    __shared__ __align__(16) uint2 gq[NROW * GQS];  // 98,136 B  (rz pair, n)
    __shared__ __align__(16) ush hl[2][HB];         // 33,792 B  (tot 157,272)

    int tid  = threadIdx.x;
    int wave = tid >> 6, lane = tid & 63;
    int l16  = lane & 15, quad = lane >> 4, quad4 = quad * 4;
    int p0   = blockIdx.x * MT;
    int bb   = p0 >> 10, lb = p0 & 1023;
    int col  = wave * 16 + l16;               // thread's single hidden col
    // weight fragment base: frag = (wave>>1)*6 + gate*2 + (wave&1)
    int fb   = ((wave >> 1) * 6 + (wave & 1)) * 4096 + lane * 8;

    // ---- stage x rows j=0..47 (token lb-15+j, zero-padded) + zero h[0] -----
    {
        const float4* x4 = (const float4*)x;
        for (int idx = tid; idx < 48 * 64; idx += 1024) {
            int j = idx >> 6, c = idx & 63;
            int tok = lb - 15 + j;
            float4 v = make_float4(0.f, 0.f, 0.f, 0.f);
            if (tok >= 0 && tok < L_) v = x4[(size_t)((bb << 10) + tok) * 64 + c];
            *(uint2*)(xs + j * HS + c * 4) = make_uint2(pk2(v.x, v.y), pk2(v.z, v.w));
        }
        for (int idx = tid; idx < HB / 2; idx += 1024)
            ((unsigned int*)(&hl[0][0]))[idx] = 0u;
    }
    __syncthreads();

    // ---- in-block gi GEMM: 48 rows x (3 gate-frags for this wave) ----------
    {
        floatx4 gacc[3][3];  // [m-tile][gate]
        {
            float ir = -L2E * (bih[col] + bhh[col]);
            float iz = -L2E * (bih[256 + col] + bhh[256 + col]);
            float in_ = 2.f * L2E * bih[512 + col];
#pragma unroll
            for (int mt = 0; mt < 3; mt++) {
                gacc[mt][0] = (floatx4){ir, ir, ir, ir};
                gacc[mt][1] = (floatx4){iz, iz, iz, iz};
                gacc[mt][2] = (floatx4){in_, in_, in_, in_};
            }
        }
        const ush* wp = Wir + fb;
#pragma unroll
        for (int ks = 0; ks < 8; ks++) {
            bf16x8 bw[3];
#pragma unroll
            for (int g = 0; g < 3; g++)
                bw[g] = *(const bf16x8*)(wp + g * 8192 + ks * 512);
#pragma unroll
            for (int mt = 0; mt < 3; mt++) {
                bf16x8 af = *(const bf16x8*)(xs + (mt * 16 + l16) * HS + ks * 32 + quad * 8);
#pragma unroll
                for (int g = 0; g < 3; g++)
                    gacc[mt][g] = __builtin_amdgcn_mfma_f32_16x16x32_bf16(
                        af, bw[g], gacc[mt][g], 0, 0, 0);
            }
        }
        // pack into gq (C/D: col=l16 -> col, row=quad4+r -> window row)
#pragma unroll
        for (int mt = 0; mt < 3; mt++)
#pragma unroll
            for (int r = 0; r < 4; r++) {
                int j = mt * 16 + quad4 + r;
                if (j < NROW) {
                    gq[j * GQS + col] = make_uint2(
                        pk2(gacc[mt][0][r], gacc[mt][1][r]),
                        (unsigned int)f2bf(gacc[mt][2][r]));
                }
            }
    }

    // ---- W_hh fragments (scaled) -> 96 regs, held across all 16 steps ------
    bf16x8 wf[3][8];
    {
        const ush* wp = Wr + fb;
#pragma unroll
        for (int g = 0; g < 3; g++)
#pragma unroll
            for (int ks = 0; ks < 8; ks++)
                wf[g][ks] = *(const bf16x8*)(wp + g * 8192 + ks * 512);
    }
    float bn = 2.f * L2E * bhh[512 + col];
    __syncthreads();  // gi pack + h[0] zero visible

    // ---- GRU loop: 3 base pointers, ALL in-loop offsets are immediates -----
    const ush*   hab = &hl[0][0] + l16 * HS + quad * 8;   // A-frag base
    ush*         hwb = &hl[0][0] + quad4 * HS + col;      // h-row base
    const uint2* gqp = gq + quad4 * GQS + col;            // gate base

    // One GRU step. RD/WR are u16 imm offsets selecting the h double buffer.
    // Epilogue: even/odd cell pairs, one v_cvt_pk_bf16_f32 per pair.
#define GRU_STEP(RD, WR)                                                      \
    {                                                                         \
        _Pragma("unroll")                                                     \
        for (int T = 0; T < 2; T++) {                                         \
            floatx4 a0 = (floatx4){0.f, 0.f, 0.f, 0.f};                       \
            floatx4 a1 = (floatx4){0.f, 0.f, 0.f, 0.f};                       \
            floatx4 a2 = (floatx4){bn, bn, bn, bn};                           \
            _Pragma("unroll")                                                 \
            for (int ks = 0; ks < 8; ks++) {                                  \
                bf16x8 af = *(const bf16x8*)(hab + (RD) + T * (16 * HS) + ks * 32); \
                a0 = __builtin_amdgcn_mfma_f32_16x16x32_bf16(af, wf[0][ks], a0, 0, 0, 0); \
                a1 = __builtin_amdgcn_mfma_f32_16x16x32_bf16(af, wf[1][ks], a1, 0, 0, 0); \
                a2 = __builtin_amdgcn_mfma_f32_16x16x32_bf16(af, wf[2][ks], a2, 0, 0, 0); \
            }                                                                 \
            _Pragma("unroll")                                                 \
            for (int pr = 0; pr < 2; pr++) {                                  \
                float hv01[2];                                                \
                _Pragma("unroll")                                             \
                for (int half = 0; half < 2; half++) {                        \
                    int r = pr * 2 + half;                                    \
                    uint2 g = gqp[(T * 16 + r) * GQS];                        \
                    float ar = a0[r] + __uint_as_float(g.x << 16);            \
                    float az = a1[r] + __uint_as_float(g.x & 0xffff0000u);    \
                    float rg = rcpf(1.f + fexp2(ar));                         \
                    float zg = rcpf(1.f + fexp2(az));                         \
                    float u  = bf2f((ush)g.y) + rg * a2[r];                   \
                    float ng = 1.f - 2.f * rcpf(fexp2(u) + 1.f);              \
                    float hprev = bf2f(hwb[(RD) + T * (16 * HS) + r * HS]);   \
                    hv01[half] = ng + zg * (hprev - ng);                      \
                }                                                             \
                unsigned int pk = pk2(hv01[0], hv01[1]);                      \
                hwb[(WR) + T * (16 * HS) + (pr * 2 + 0) * HS] = (ush)(pk & 0xffffu); \
                hwb[(WR) + T * (16 * HS) + (pr * 2 + 1) * HS] = (ush)(pk >> 16);     \
            }                                                                 \
        }                                                                     \
        __syncthreads();                                                      \
        gqp += GQS;                                                           \
    }

#pragma unroll 1
    for (int tt = 0; tt < K_ / 2; tt++) {
        GRU_STEP(0, HB);   // even t: read hl[0], write hl[1]
        GRU_STEP(HB, 0);   // odd  t: read hl[1], write hl[0]
    }
#undef GRU_STEP

    // ---- final h (in hl[0] after 16 steps) -> out (fp32), own cells --------
#pragma unroll
    for (int T = 0; T < 2; T++)
#pragma unroll
        for (int r = 0; r < 4; r++) {
            int row = T * 16 + quad4 + r;
            out[(size_t)(p0 + row) * H_ + col] = bf2f(hl[0][row * HS + col]);
        }
}

extern "C" void kernel_launch(void* const* d_in, const int* in_sizes, int n_in,
                              void* d_out, int out_size, void* d_ws, size_t ws_size,
                              hipStream_t stream) {
    const float* x    = (const float*)d_in[0];
    const float* W_ih = (const float*)d_in[1];
    const float* W_hh = (const float*)d_in[2];
    const float* b_ih = (const float*)d_in[3];
    const float* b_hh = (const float*)d_in[4];
    float* out = (float*)d_out;

    // ws layout (bytes): Wir 393,216 | Wr 393,216  (scaled, wave-blocked)
    char* ws = (char*)d_ws;
    ush* Wir = (ush*)ws;
    ush* Wr  = (ush*)(ws + 393216);

    wprep<<<2 * NCHUNK / 256, 256, 0, stream>>>(W_ih, W_hh, Wir, Wr);
    rnn_fused<<<B_ * L_ / MT, 1024, 0, stream>>>(x, Wir, Wr, b_ih, b_hh, out);
}